// Round 13
// baseline (67.123 us; speedup 1.0000x reference)
//
#include <hip/hip_runtime.h>
#include <hip/hip_bf16.h>

#define B_   16
#define L_   256
#define D_   512
#define C_   8
#define P_   12
#define LOUT 244
#define O_   512
#define GM   3904   // 16*244 rows per channel
#define BM   128
#define BN   256
#define BK   32
#define NMT  31     // ceil(3904/128)
#define NNT  2
#define NSTEP 16    // D_/BK

typedef __attribute__((ext_vector_type(8))) short bf16x8;
typedef __attribute__((ext_vector_type(4))) float f32x4;

__device__ __forceinline__ unsigned short f2bf(float f) {
    unsigned int u = __float_as_uint(f);
    unsigned int r = (u + 0x7FFFu + ((u >> 16) & 1u)) >> 16;
    return (unsigned short)r;
}

__device__ __forceinline__ void async_copy16(const void* g, void* l) {
    __builtin_amdgcn_global_load_lds(
        (const __attribute__((address_space(1))) unsigned int*)g,
        (__attribute__((address_space(3))) unsigned int*)l, 16, 0, 0);
}

// ---------------------------------------------------------------------------
// prep (round-2 verbatim, verified passing 4x):
//   blocks [0,976):  tmp[c][b][l][d] = sum_p Wt[c,p]*inp[b,l+p,d] (bf16);
//                    one inp read serves all 8 channels.
//   blocks [976,3024): Ws f32 -> bf16.
// ---------------------------------------------------------------------------
__global__ __launch_bounds__(256) void prep(const float* __restrict__ inp,
                                            const float* __restrict__ Ws,
                                            const float* __restrict__ Wt,
                                            unsigned short* __restrict__ tmp,
                                            unsigned short* __restrict__ wsb) {
    int bid = blockIdx.x;
    int tid = threadIdx.x;

    if (bid >= 976) {                       // ---- Ws convert path ----
        int g = (bid - 976) * 256 + tid;    // 524288 float4s
        float4 v = ((const float4*)Ws)[g];
        ushort4 o;
        o.x = f2bf(v.x); o.y = f2bf(v.y); o.z = f2bf(v.z); o.w = f2bf(v.w);
        ((ushort4*)wsb)[g] = o;
        return;
    }

    // ---- FIR path ----
    __shared__ float wt_s[C_][P_];
    if (tid < C_ * P_) wt_s[tid / P_][tid % P_] = Wt[tid];
    __syncthreads();

    int b = bid / 61, lg = bid % 61;
    int l0 = lg * 4;
    int d0 = tid * 2;

    float2 rows[15];
    const float* ibase = inp + ((size_t)b * L_ + l0) * D_ + d0;
#pragma unroll
    for (int j = 0; j < 15; ++j)
        rows[j] = *(const float2*)(ibase + (size_t)j * D_);

#pragma unroll
    for (int c = 0; c < C_; ++c) {
        float w[P_];
#pragma unroll
        for (int p = 0; p < P_; ++p) w[p] = wt_s[c][p];
        unsigned short* ob = tmp + (((size_t)(c * B_ + b)) * LOUT + l0) * D_ + d0;
#pragma unroll
        for (int j = 0; j < 4; ++j) {
            float vx = 0.f, vy = 0.f;
#pragma unroll
            for (int p = 0; p < P_; ++p) {
                vx += w[p] * rows[j + p].x;
                vy += w[p] * rows[j + p].y;
            }
            ushort2 ov; ov.x = f2bf(vx); ov.y = f2bf(vy);
            *(ushort2*)(ob + (size_t)j * D_) = ov;
        }
    }
}

// ---------------------------------------------------------------------------
// gemm (round-12 verbatim): per (c,mt,nt): out = tmp_c . Ws_c^T + bias
//   128x256 tile, BK=32, 512 thr = 8 waves (2m x 4n), wave tile 64x64.
//   Triple buffer, one barrier per K-step, counted vmcnt (provable scheme).
// ---------------------------------------------------------------------------
__global__ __launch_bounds__(512, 4) void gemm_k(const unsigned short* __restrict__ tmp,
                                                 const unsigned short* __restrict__ wsb,
                                                 const float* __restrict__ bs,
                                                 const float* __restrict__ Wt,
                                                 const float* __restrict__ bt,
                                                 float* __restrict__ out) {
    __shared__ unsigned short As[3][BM * BK];   // 3 x 8 KB
    __shared__ unsigned short Bs[3][BN * BK];   // 3 x 16 KB

    int bid = blockIdx.x;
    int c  = bid & 7;
    int t2 = bid >> 3;                 // 0..61
    int nt = t2 & 1;
    int mt = t2 >> 1;                  // 0..30
    int row0 = mt * BM;
    int o0   = nt * BN;
    int tid = threadIdx.x, lane = tid & 63, wid = tid >> 6;
    int wm = wid >> 2, wn = wid & 3;   // 2 x 4 wave grid; wave tile 64x64

    const unsigned short* Ab = tmp + (size_t)c * GM * D_;
    const unsigned short* Bb = wsb + ((size_t)c * O_ + o0) * D_;

    f32x4 acc[4][4];
#pragma unroll
    for (int m = 0; m < 4; ++m)
#pragma unroll
        for (int n = 0; n < 4; ++n)
            acc[m][n] = (f32x4){0.f, 0.f, 0.f, 0.f};

    // per stage: A 512 chunks (1/thread) + B 1024 chunks (2/thread) = 3 insts
#define STAGE(bi, kb)                                                         \
    {                                                                         \
        int qa = tid;                                                         \
        int rowa = qa >> 2, cca = qa & 3;                                     \
        int sca = cca ^ (rowa & 3);                                           \
        int ar = row0 + rowa; if (ar > GM - 1) ar = GM - 1;                   \
        async_copy16(Ab + (size_t)ar * D_ + (kb) + sca * 8,                   \
                     (unsigned short*)As[bi] + qa * 8);                       \
        _Pragma("unroll")                                                     \
        for (int h = 0; h < 2; ++h) {                                         \
            int q = h * 512 + tid;                                            \
            int row = q >> 2, cc = q & 3;                                     \
            int sc = cc ^ (row & 3);                                          \
            async_copy16(Bb + (size_t)row * D_ + (kb) + sc * 8,               \
                         (unsigned short*)Bs[bi] + q * 8);                    \
        }                                                                     \
    }

    // one K=32 slice: 4x4 MFMA per wave
#define MFMA_STEP(bi)                                                         \
    {                                                                         \
        bf16x8 af[4], bq[4];                                                  \
        _Pragma("unroll")                                                     \
        for (int m = 0; m < 4; ++m) {                                         \
            int r = wm * 64 + m * 16 + (lane & 15);                           \
            af[m] = *(const bf16x8*)&As[bi][r * BK +                          \
                    (((lane >> 4) ^ (r & 3)) << 3)];                          \
        }                                                                     \
        _Pragma("unroll")                                                     \
        for (int n = 0; n < 4; ++n) {                                         \
            int o = wn * 64 + n * 16 + (lane & 15);                           \
            bq[n] = *(const bf16x8*)&Bs[bi][o * BK +                          \
                    (((lane >> 4) ^ (o & 3)) << 3)];                          \
        }                                                                     \
        _Pragma("unroll")                                                     \
        for (int m = 0; m < 4; ++m)                                           \
            _Pragma("unroll")                                                 \
            for (int n = 0; n < 4; ++n)                                       \
                acc[m][n] = __builtin_amdgcn_mfma_f32_16x16x32_bf16(          \
                    af[m], bq[n], acc[m][n], 0, 0, 0);                        \
    }

    // ---- prologue: stage 0,1; drain both (provable); barrier ----
    STAGE(0, 0)
    STAGE(1, BK)
    asm volatile("s_waitcnt vmcnt(0)" ::: "memory");
    __builtin_amdgcn_sched_barrier(0);
    asm volatile("s_barrier" ::: "memory");

    // ---- K-loop: 16 steps, 3-buffer, ONE barrier per step ----
#pragma unroll
    for (int t = 0; t < NSTEP; ++t) {
        MFMA_STEP(t % 3)
        if (t == NSTEP - 1) break;
        asm volatile("s_waitcnt lgkmcnt(0)" ::: "memory");
        __builtin_amdgcn_sched_barrier(0);
        if (t + 2 < NSTEP) STAGE((t + 2) % 3, (t + 2) * BK)
        if (t < NSTEP - 2)
            asm volatile("s_waitcnt vmcnt(3)" ::: "memory");  // certify t+1
        else
            asm volatile("s_waitcnt vmcnt(0)" ::: "memory");  // tail
        __builtin_amdgcn_sched_barrier(0);
        asm volatile("s_barrier" ::: "memory");   // step separator
    }

    // ---- bias + store ----
    float S = 0.f;
#pragma unroll
    for (int p = 0; p < P_; ++p) S += Wt[c * P_ + p];
    float btc = bt[c];

#pragma unroll
    for (int m = 0; m < 4; ++m) {
        int rb = row0 + wm * 64 + m * 16 + ((lane >> 4) << 2);
#pragma unroll
        for (int n = 0; n < 4; ++n) {
            int col = o0 + wn * 64 + n * 16 + (lane & 15);
            float add = bs[c * O_ + col] * S + btc;
#pragma unroll
            for (int i = 0; i < 4; ++i) {
                int r = rb + i;
                if (r < GM)
                    out[((size_t)r * C_ + c) * O_ + col] = acc[m][n][i] + add;
            }
        }
    }
#undef STAGE
#undef MFMA_STEP
}

// ---------------------------------------------------------------------------
// Fallback (ws too small): slow but correct, no workspace.
// ---------------------------------------------------------------------------
__global__ __launch_bounds__(256) void naive_k(const float* __restrict__ inp,
                                               const float* __restrict__ Ws,
                                               const float* __restrict__ bs,
                                               const float* __restrict__ Wt,
                                               const float* __restrict__ bt,
                                               float* __restrict__ out) {
    __shared__ float tmp[D_];
    int bid = blockIdx.x;
    int c = bid & 7; int r = bid >> 3;
    int l = r % LOUT; int b = r / LOUT;
    int tid = threadIdx.x;

    for (int d = tid; d < D_; d += 256) {
        float s = 0.f;
        for (int p = 0; p < P_; ++p)
            s += Wt[c * P_ + p] * inp[((size_t)b * L_ + l + p) * D_ + d];
        tmp[d] = s;
    }
    __syncthreads();
    float S = 0.f;
    for (int p = 0; p < P_; ++p) S += Wt[c * P_ + p];
    for (int o = tid; o < O_; o += 256) {
        const float* wrow = Ws + ((size_t)c * O_ + o) * D_;
        float s = 0.f;
        for (int d = 0; d < D_; ++d) s += wrow[d] * tmp[d];
        out[(((size_t)b * LOUT + l) * C_ + c) * O_ + o] =
            s + bs[c * O_ + o] * S + bt[c];
    }
}

extern "C" void kernel_launch(void* const* d_in, const int* in_sizes, int n_in,
                              void* d_out, int out_size, void* d_ws, size_t ws_size,
                              hipStream_t stream) {
    const float* inp = (const float*)d_in[0];
    const float* Ws  = (const float*)d_in[1];
    const float* bs  = (const float*)d_in[2];
    const float* Wt  = (const float*)d_in[3];
    const float* bt  = (const float*)d_in[4];
    float* out = (float*)d_out;

    const size_t TMPB = (size_t)C_ * GM * D_ * 2;   // 31,981,568
    const size_t WSBB = (size_t)C_ * O_ * D_ * 2;   //  4,194,304

    if (ws_size >= TMPB + WSBB) {
        unsigned short* tmpb = (unsigned short*)d_ws;
        unsigned short* wsb  = (unsigned short*)((char*)d_ws + TMPB);
        prep<<<3024, 256, 0, stream>>>(inp, Ws, Wt, tmpb, wsb);
        gemm_k<<<NMT * NNT * C_, 512, 0, stream>>>(tmpb, wsb, bs, Wt, bt, out);
        // INSTRUMENTATION (round 13): second identical gemm launch.
        // Idempotent (reads unchanged tmp/wsb, rewrites identical out).
        // Total-time delta vs round 12 measures gemm's duration directly,
        // disambiguating the prep/gemm split hidden below rocprof's top-5.
        gemm_k<<<NMT * NNT * C_, 512, 0, stream>>>(tmpb, wsb, bs, Wt, bt, out);
    } else {
        naive_k<<<B_ * LOUT * C_, 256, 0, stream>>>(inp, Ws, bs, Wt, bt, out);
    }
}

// Round 14
// 45.359 us; speedup vs baseline: 1.4798x; 1.4798x over previous
//
#include <hip/hip_runtime.h>
#include <hip/hip_bf16.h>

#define B_   16
#define L_   256
#define D_   512
#define C_   8
#define P_   12
#define LOUT 244
#define O_   512
#define GM   3904   // 16*244 rows per channel
#define BM   128
#define BN   256
#define BK   32
#define NMT  31     // ceil(3904/128)
#define NNT  2
#define NSTEP 16    // D_/BK
#define NFIRB 256   // 16 batches x 16 row-groups (16 rows each)

typedef __attribute__((ext_vector_type(8))) short bf16x8;
typedef __attribute__((ext_vector_type(4))) float f32x4;

__device__ __forceinline__ unsigned short f2bf(float f) {
    unsigned int u = __float_as_uint(f);
    unsigned int r = (u + 0x7FFFu + ((u >> 16) & 1u)) >> 16;
    return (unsigned short)r;
}

__device__ __forceinline__ void async_copy16(const void* g, void* l) {
    __builtin_amdgcn_global_load_lds(
        (const __attribute__((address_space(1))) unsigned int*)g,
        (__attribute__((address_space(3))) unsigned int*)l, 16, 0, 0);
}

// ---------------------------------------------------------------------------
// prep v2 (round-14): Guideline-13 widths.
//   blocks [0,256):  FIR. Block = batch b x 16 rows (2 rg x 8). Thread =
//     one d-quad (float4 loads) x 8 rows x 8 channels, ushort4 stores.
//     Read redundancy 2.4x (19 rows per 8 outputs); 19.9 MB read.
//   blocks [256,2304): Ws f32 -> bf16 (one float4 per thread).
// ---------------------------------------------------------------------------
__global__ __launch_bounds__(256) void prep(const float* __restrict__ inp,
                                            const float* __restrict__ Ws,
                                            const float* __restrict__ Wt,
                                            unsigned short* __restrict__ tmp,
                                            unsigned short* __restrict__ wsb) {
    int bid = blockIdx.x;
    int tid = threadIdx.x;

    if (bid >= NFIRB) {                     // ---- Ws convert path ----
        int g = (bid - NFIRB) * 256 + tid;  // 524288 float4s
        float4 v = ((const float4*)Ws)[g];
        ushort4 o;
        o.x = f2bf(v.x); o.y = f2bf(v.y); o.z = f2bf(v.z); o.w = f2bf(v.w);
        ((ushort4*)wsb)[g] = o;
        return;
    }

    // ---- FIR path ----
    __shared__ float wt_s[C_][P_];
    if (tid < C_ * P_) wt_s[tid / P_][tid % P_] = Wt[tid];
    __syncthreads();

    int b   = bid >> 4;                 // 0..15
    int lgr = bid & 15;                 // 0..15, 16 rows each
    int rg  = tid >> 7;                 // 0 or 1 (8-row half)
    int dq  = tid & 127;                // d-quad index
    int d0  = dq * 4;
    int l0  = lgr * 16 + rg * 8;        // first output row of this half
    if (l0 >= LOUT) return;             // tail: lgr=15, rg=1 idle
    int rows = (l0 + 8 <= LOUT) ? 8 : (LOUT - l0);   // 8, or 4 at lgr=15

    // burst-load 19 input rows (rows+11 <= 19); l0+18 <= 243+... max l0=240
    // (rows=4): 240+14 = 254 < 256 in-bounds; full: 232+18 = 250 < 256.
    float4 rv[19];
    const float* ibase = inp + ((size_t)b * L_ + l0) * D_ + d0;
#pragma unroll
    for (int j = 0; j < 19; ++j)
        rv[j] = (j < rows + 11) ? *(const float4*)(ibase + (size_t)j * D_)
                                : (float4){0.f, 0.f, 0.f, 0.f};

#pragma unroll
    for (int c = 0; c < C_; ++c) {
        float w[P_];
#pragma unroll
        for (int p = 0; p < P_; ++p) w[p] = wt_s[c][p];
        unsigned short* ob = tmp + (((size_t)(c * B_ + b)) * LOUT + l0) * D_ + d0;
#pragma unroll
        for (int j = 0; j < 8; ++j) {
            if (j < rows) {
                float sx = 0.f, sy = 0.f, sz = 0.f, sw = 0.f;
#pragma unroll
                for (int p = 0; p < P_; ++p) {
                    sx += w[p] * rv[j + p].x;
                    sy += w[p] * rv[j + p].y;
                    sz += w[p] * rv[j + p].z;
                    sw += w[p] * rv[j + p].w;
                }
                ushort4 ov;
                ov.x = f2bf(sx); ov.y = f2bf(sy);
                ov.z = f2bf(sz); ov.w = f2bf(sw);
                *(ushort4*)(ob + (size_t)j * D_) = ov;
            }
        }
    }
}

// ---------------------------------------------------------------------------
// gemm (round-12 verbatim, measured 24.4 us): out = tmp_c . Ws_c^T + bias
//   128x256 tile, BK=32, 512 thr = 8 waves (2m x 4n), wave tile 64x64.
//   Triple buffer, one barrier per K-step, counted vmcnt (provable scheme).
// ---------------------------------------------------------------------------
__global__ __launch_bounds__(512, 4) void gemm_k(const unsigned short* __restrict__ tmp,
                                                 const unsigned short* __restrict__ wsb,
                                                 const float* __restrict__ bs,
                                                 const float* __restrict__ Wt,
                                                 const float* __restrict__ bt,
                                                 float* __restrict__ out) {
    __shared__ unsigned short As[3][BM * BK];   // 3 x 8 KB
    __shared__ unsigned short Bs[3][BN * BK];   // 3 x 16 KB

    int bid = blockIdx.x;
    int c  = bid & 7;
    int t2 = bid >> 3;                 // 0..61
    int nt = t2 & 1;
    int mt = t2 >> 1;                  // 0..30
    int row0 = mt * BM;
    int o0   = nt * BN;
    int tid = threadIdx.x, lane = tid & 63, wid = tid >> 6;
    int wm = wid >> 2, wn = wid & 3;   // 2 x 4 wave grid; wave tile 64x64

    const unsigned short* Ab = tmp + (size_t)c * GM * D_;
    const unsigned short* Bb = wsb + ((size_t)c * O_ + o0) * D_;

    f32x4 acc[4][4];
#pragma unroll
    for (int m = 0; m < 4; ++m)
#pragma unroll
        for (int n = 0; n < 4; ++n)
            acc[m][n] = (f32x4){0.f, 0.f, 0.f, 0.f};

    // per stage: A 512 chunks (1/thread) + B 1024 chunks (2/thread) = 3 insts
#define STAGE(bi, kb)                                                         \
    {                                                                         \
        int qa = tid;                                                         \
        int rowa = qa >> 2, cca = qa & 3;                                     \
        int sca = cca ^ (rowa & 3);                                           \
        int ar = row0 + rowa; if (ar > GM - 1) ar = GM - 1;                   \
        async_copy16(Ab + (size_t)ar * D_ + (kb) + sca * 8,                   \
                     (unsigned short*)As[bi] + qa * 8);                       \
        _Pragma("unroll")                                                     \
        for (int h = 0; h < 2; ++h) {                                         \
            int q = h * 512 + tid;                                            \
            int row = q >> 2, cc = q & 3;                                     \
            int sc = cc ^ (row & 3);                                          \
            async_copy16(Bb + (size_t)row * D_ + (kb) + sc * 8,               \
                         (unsigned short*)Bs[bi] + q * 8);                    \
        }                                                                     \
    }

    // one K=32 slice: 4x4 MFMA per wave
#define MFMA_STEP(bi)                                                         \
    {                                                                         \
        bf16x8 af[4], bq[4];                                                  \
        _Pragma("unroll")                                                     \
        for (int m = 0; m < 4; ++m) {                                         \
            int r = wm * 64 + m * 16 + (lane & 15);                           \
            af[m] = *(const bf16x8*)&As[bi][r * BK +                          \
                    (((lane >> 4) ^ (r & 3)) << 3)];                          \
        }                                                                     \
        _Pragma("unroll")                                                     \
        for (int n = 0; n < 4; ++n) {                                         \
            int o = wn * 64 + n * 16 + (lane & 15);                           \
            bq[n] = *(const bf16x8*)&Bs[bi][o * BK +                          \
                    (((lane >> 4) ^ (o & 3)) << 3)];                          \
        }                                                                     \
        _Pragma("unroll")                                                     \
        for (int m = 0; m < 4; ++m)                                           \
            _Pragma("unroll")                                                 \
            for (int n = 0; n < 4; ++n)                                       \
                acc[m][n] = __builtin_amdgcn_mfma_f32_16x16x32_bf16(          \
                    af[m], bq[n], acc[m][n], 0, 0, 0);                        \
    }

    // ---- prologue: stage 0,1; drain both (provable); barrier ----
    STAGE(0, 0)
    STAGE(1, BK)
    asm volatile("s_waitcnt vmcnt(0)" ::: "memory");
    __builtin_amdgcn_sched_barrier(0);
    asm volatile("s_barrier" ::: "memory");

    // ---- K-loop: 16 steps, 3-buffer, ONE barrier per step ----
#pragma unroll
    for (int t = 0; t < NSTEP; ++t) {
        MFMA_STEP(t % 3)
        if (t == NSTEP - 1) break;
        asm volatile("s_waitcnt lgkmcnt(0)" ::: "memory");
        __builtin_amdgcn_sched_barrier(0);
        if (t + 2 < NSTEP) STAGE((t + 2) % 3, (t + 2) * BK)
        if (t < NSTEP - 2)
            asm volatile("s_waitcnt vmcnt(3)" ::: "memory");  // certify t+1
        else
            asm volatile("s_waitcnt vmcnt(0)" ::: "memory");  // tail
        __builtin_amdgcn_sched_barrier(0);
        asm volatile("s_barrier" ::: "memory");   // step separator
    }

    // ---- bias + store ----
    float S = 0.f;
#pragma unroll
    for (int p = 0; p < P_; ++p) S += Wt[c * P_ + p];
    float btc = bt[c];

#pragma unroll
    for (int m = 0; m < 4; ++m) {
        int rb = row0 + wm * 64 + m * 16 + ((lane >> 4) << 2);
#pragma unroll
        for (int n = 0; n < 4; ++n) {
            int col = o0 + wn * 64 + n * 16 + (lane & 15);
            float add = bs[c * O_ + col] * S + btc;
#pragma unroll
            for (int i = 0; i < 4; ++i) {
                int r = rb + i;
                if (r < GM)
                    out[((size_t)r * C_ + c) * O_ + col] = acc[m][n][i] + add;
            }
        }
    }
#undef STAGE
#undef MFMA_STEP
}

// ---------------------------------------------------------------------------
// Fallback (ws too small): slow but correct, no workspace.
// ---------------------------------------------------------------------------
__global__ __launch_bounds__(256) void naive_k(const float* __restrict__ inp,
                                               const float* __restrict__ Ws,
                                               const float* __restrict__ bs,
                                               const float* __restrict__ Wt,
                                               const float* __restrict__ bt,
                                               float* __restrict__ out) {
    __shared__ float tmp[D_];
    int bid = blockIdx.x;
    int c = bid & 7; int r = bid >> 3;
    int l = r % LOUT; int b = r / LOUT;
    int tid = threadIdx.x;

    for (int d = tid; d < D_; d += 256) {
        float s = 0.f;
        for (int p = 0; p < P_; ++p)
            s += Wt[c * P_ + p] * inp[((size_t)b * L_ + l + p) * D_ + d];
        tmp[d] = s;
    }
    __syncthreads();
    float S = 0.f;
    for (int p = 0; p < P_; ++p) S += Wt[c * P_ + p];
    for (int o = tid; o < O_; o += 256) {
        const float* wrow = Ws + ((size_t)c * O_ + o) * D_;
        float s = 0.f;
        for (int d = 0; d < D_; ++d) s += wrow[d] * tmp[d];
        out[(((size_t)b * LOUT + l) * C_ + c) * O_ + o] =
            s + bs[c * O_ + o] * S + bt[c];
    }
}

extern "C" void kernel_launch(void* const* d_in, const int* in_sizes, int n_in,
                              void* d_out, int out_size, void* d_ws, size_t ws_size,
                              hipStream_t stream) {
    const float* inp = (const float*)d_in[0];
    const float* Ws  = (const float*)d_in[1];
    const float* bs  = (const float*)d_in[2];
    const float* Wt  = (const float*)d_in[3];
    const float* bt  = (const float*)d_in[4];
    float* out = (float*)d_out;

    const size_t TMPB = (size_t)C_ * GM * D_ * 2;   // 31,981,568
    const size_t WSBB = (size_t)C_ * O_ * D_ * 2;   //  4,194,304

    if (ws_size >= TMPB + WSBB) {
        unsigned short* tmpb = (unsigned short*)d_ws;
        unsigned short* wsb  = (unsigned short*)((char*)d_ws + TMPB);
        prep<<<NFIRB + 2048, 256, 0, stream>>>(inp, Ws, Wt, tmpb, wsb);
        gemm_k<<<NMT * NNT * C_, 512, 0, stream>>>(tmpb, wsb, bs, Wt, bt, out);
    } else {
        naive_k<<<B_ * LOUT * C_, 256, 0, stream>>>(inp, Ws, bs, Wt, bt, out);
    }
}

// Round 15
// 41.433 us; speedup vs baseline: 1.6201x; 1.0948x over previous
//
#include <hip/hip_runtime.h>
#include <hip/hip_bf16.h>

#define B_   16
#define L_   256
#define D_   512
#define C_   8
#define P_   12
#define LOUT 244
#define O_   512
#define GM   3904   // 16*244 rows per channel
#define BM   128
#define BN   256
#define BK   32
#define NMT  31     // ceil(3904/128)
#define NNT  2
#define NSTEP 16    // D_/BK
#define NFIRB 488   // 16 b x 61 lg / 2 tasks per block

typedef __attribute__((ext_vector_type(8))) short bf16x8;
typedef __attribute__((ext_vector_type(4))) float f32x4;

__device__ __forceinline__ unsigned short f2bf(float f) {
    unsigned int u = __float_as_uint(f);
    unsigned int r = (u + 0x7FFFu + ((u >> 16) & 1u)) >> 16;
    return (unsigned short)r;
}

__device__ __forceinline__ void async_copy16(const void* g, void* l) {
    __builtin_amdgcn_global_load_lds(
        (const __attribute__((address_space(1))) unsigned int*)g,
        (__attribute__((address_space(3))) unsigned int*)l, 16, 0, 0);
}

// ---------------------------------------------------------------------------
// prep v3: r2 task shape (4-row window, 61 l-groups) + float4/ushort4 widths.
//   blocks [0,488):  FIR. Block = 2 tasks; task = (b, lg): 4 rows x 128
//     d-quads. Thread: 15 float4 loads (sliding window), 8 ch x 4 rows,
//     ushort4 stores. 1952 waves (~2/SIMD) + convert blocks fill tail.
//   blocks [488,2536): Ws f32 -> bf16 (one float4 per thread).
// ---------------------------------------------------------------------------
__global__ __launch_bounds__(256) void prep(const float* __restrict__ inp,
                                            const float* __restrict__ Ws,
                                            const float* __restrict__ Wt,
                                            unsigned short* __restrict__ tmp,
                                            unsigned short* __restrict__ wsb) {
    int bid = blockIdx.x;
    int tid = threadIdx.x;

    if (bid >= NFIRB) {                     // ---- Ws convert path ----
        int g = (bid - NFIRB) * 256 + tid;  // 524288 float4s
        float4 v = ((const float4*)Ws)[g];
        ushort4 o;
        o.x = f2bf(v.x); o.y = f2bf(v.y); o.z = f2bf(v.z); o.w = f2bf(v.w);
        ((ushort4*)wsb)[g] = o;
        return;
    }

    // ---- FIR path ----
    __shared__ float wt_s[C_][P_];
    if (tid < C_ * P_) wt_s[tid / P_][tid % P_] = Wt[tid];
    __syncthreads();

    int task = bid * 2 + (tid >> 7);    // 0..975 = b*61 + lg
    int dq   = tid & 127;               // d-quad
    int b  = task / 61, lg = task % 61;
    int l0 = lg * 4;
    int d0 = dq * 4;

    // window: rows l0..l0+14 (l0 <= 240, l0+14 = 254 < 256: in-bounds)
    float4 rv[15];
    const float* ibase = inp + ((size_t)b * L_ + l0) * D_ + d0;
#pragma unroll
    for (int j = 0; j < 15; ++j)
        rv[j] = *(const float4*)(ibase + (size_t)j * D_);

#pragma unroll
    for (int c = 0; c < C_; ++c) {
        float w[P_];
#pragma unroll
        for (int p = 0; p < P_; ++p) w[p] = wt_s[c][p];
        unsigned short* ob = tmp + (((size_t)(c * B_ + b)) * LOUT + l0) * D_ + d0;
#pragma unroll
        for (int j = 0; j < 4; ++j) {
            float sx = 0.f, sy = 0.f, sz = 0.f, sw = 0.f;
#pragma unroll
            for (int p = 0; p < P_; ++p) {
                sx += w[p] * rv[j + p].x;
                sy += w[p] * rv[j + p].y;
                sz += w[p] * rv[j + p].z;
                sw += w[p] * rv[j + p].w;
            }
            ushort4 ov;
            ov.x = f2bf(sx); ov.y = f2bf(sy);
            ov.z = f2bf(sz); ov.w = f2bf(sw);
            *(ushort4*)(ob + (size_t)j * D_) = ov;
        }
    }
}

// ---------------------------------------------------------------------------
// gemm (round-12 verbatim, measured 24.4 us): out = tmp_c . Ws_c^T + bias
//   128x256 tile, BK=32, 512 thr = 8 waves (2m x 4n), wave tile 64x64.
//   Triple buffer, one barrier per K-step, counted vmcnt (provable scheme).
// ---------------------------------------------------------------------------
__global__ __launch_bounds__(512, 4) void gemm_k(const unsigned short* __restrict__ tmp,
                                                 const unsigned short* __restrict__ wsb,
                                                 const float* __restrict__ bs,
                                                 const float* __restrict__ Wt,
                                                 const float* __restrict__ bt,
                                                 float* __restrict__ out) {
    __shared__ unsigned short As[3][BM * BK];   // 3 x 8 KB
    __shared__ unsigned short Bs[3][BN * BK];   // 3 x 16 KB

    int bid = blockIdx.x;
    int c  = bid & 7;
    int t2 = bid >> 3;                 // 0..61
    int nt = t2 & 1;
    int mt = t2 >> 1;                  // 0..30
    int row0 = mt * BM;
    int o0   = nt * BN;
    int tid = threadIdx.x, lane = tid & 63, wid = tid >> 6;
    int wm = wid >> 2, wn = wid & 3;   // 2 x 4 wave grid; wave tile 64x64

    const unsigned short* Ab = tmp + (size_t)c * GM * D_;
    const unsigned short* Bb = wsb + ((size_t)c * O_ + o0) * D_;

    f32x4 acc[4][4];
#pragma unroll
    for (int m = 0; m < 4; ++m)
#pragma unroll
        for (int n = 0; n < 4; ++n)
            acc[m][n] = (f32x4){0.f, 0.f, 0.f, 0.f};

    // per stage: A 512 chunks (1/thread) + B 1024 chunks (2/thread) = 3 insts
#define STAGE(bi, kb)                                                         \
    {                                                                         \
        int qa = tid;                                                         \
        int rowa = qa >> 2, cca = qa & 3;                                     \
        int sca = cca ^ (rowa & 3);                                           \
        int ar = row0 + rowa; if (ar > GM - 1) ar = GM - 1;                   \
        async_copy16(Ab + (size_t)ar * D_ + (kb) + sca * 8,                   \
                     (unsigned short*)As[bi] + qa * 8);                       \
        _Pragma("unroll")                                                     \
        for (int h = 0; h < 2; ++h) {                                         \
            int q = h * 512 + tid;                                            \
            int row = q >> 2, cc = q & 3;                                     \
            int sc = cc ^ (row & 3);                                          \
            async_copy16(Bb + (size_t)row * D_ + (kb) + sc * 8,               \
                         (unsigned short*)Bs[bi] + q * 8);                    \
        }                                                                     \
    }

    // one K=32 slice: 4x4 MFMA per wave
#define MFMA_STEP(bi)                                                         \
    {                                                                         \
        bf16x8 af[4], bq[4];                                                  \
        _Pragma("unroll")                                                     \
        for (int m = 0; m < 4; ++m) {                                         \
            int r = wm * 64 + m * 16 + (lane & 15);                           \
            af[m] = *(const bf16x8*)&As[bi][r * BK +                          \
                    (((lane >> 4) ^ (r & 3)) << 3)];                          \
        }                                                                     \
        _Pragma("unroll")                                                     \
        for (int n = 0; n < 4; ++n) {                                         \
            int o = wn * 64 + n * 16 + (lane & 15);                           \
            bq[n] = *(const bf16x8*)&Bs[bi][o * BK +                          \
                    (((lane >> 4) ^ (o & 3)) << 3)];                          \
        }                                                                     \
        _Pragma("unroll")                                                     \
        for (int m = 0; m < 4; ++m)                                           \
            _Pragma("unroll")                                                 \
            for (int n = 0; n < 4; ++n)                                       \
                acc[m][n] = __builtin_amdgcn_mfma_f32_16x16x32_bf16(          \
                    af[m], bq[n], acc[m][n], 0, 0, 0);                        \
    }

    // ---- prologue: stage 0,1; drain both (provable); barrier ----
    STAGE(0, 0)
    STAGE(1, BK)
    asm volatile("s_waitcnt vmcnt(0)" ::: "memory");
    __builtin_amdgcn_sched_barrier(0);
    asm volatile("s_barrier" ::: "memory");

    // ---- K-loop: 16 steps, 3-buffer, ONE barrier per step ----
#pragma unroll
    for (int t = 0; t < NSTEP; ++t) {
        MFMA_STEP(t % 3)
        if (t == NSTEP - 1) break;
        asm volatile("s_waitcnt lgkmcnt(0)" ::: "memory");
        __builtin_amdgcn_sched_barrier(0);
        if (t + 2 < NSTEP) STAGE((t + 2) % 3, (t + 2) * BK)
        if (t < NSTEP - 2)
            asm volatile("s_waitcnt vmcnt(3)" ::: "memory");  // certify t+1
        else
            asm volatile("s_waitcnt vmcnt(0)" ::: "memory");  // tail
        __builtin_amdgcn_sched_barrier(0);
        asm volatile("s_barrier" ::: "memory");   // step separator
    }

    // ---- bias + store ----
    float S = 0.f;
#pragma unroll
    for (int p = 0; p < P_; ++p) S += Wt[c * P_ + p];
    float btc = bt[c];

#pragma unroll
    for (int m = 0; m < 4; ++m) {
        int rb = row0 + wm * 64 + m * 16 + ((lane >> 4) << 2);
#pragma unroll
        for (int n = 0; n < 4; ++n) {
            int col = o0 + wn * 64 + n * 16 + (lane & 15);
            float add = bs[c * O_ + col] * S + btc;
#pragma unroll
            for (int i = 0; i < 4; ++i) {
                int r = rb + i;
                if (r < GM)
                    out[((size_t)r * C_ + c) * O_ + col] = acc[m][n][i] + add;
            }
        }
    }
#undef STAGE
#undef MFMA_STEP
}

// ---------------------------------------------------------------------------
// Fallback (ws too small): slow but correct, no workspace.
// ---------------------------------------------------------------------------
__global__ __launch_bounds__(256) void naive_k(const float* __restrict__ inp,
                                               const float* __restrict__ Ws,
                                               const float* __restrict__ bs,
                                               const float* __restrict__ Wt,
                                               const float* __restrict__ bt,
                                               float* __restrict__ out) {
    __shared__ float tmp[D_];
    int bid = blockIdx.x;
    int c = bid & 7; int r = bid >> 3;
    int l = r % LOUT; int b = r / LOUT;
    int tid = threadIdx.x;

    for (int d = tid; d < D_; d += 256) {
        float s = 0.f;
        for (int p = 0; p < P_; ++p)
            s += Wt[c * P_ + p] * inp[((size_t)b * L_ + l + p) * D_ + d];
        tmp[d] = s;
    }
    __syncthreads();
    float S = 0.f;
    for (int p = 0; p < P_; ++p) S += Wt[c * P_ + p];
    for (int o = tid; o < O_; o += 256) {
        const float* wrow = Ws + ((size_t)c * O_ + o) * D_;
        float s = 0.f;
        for (int d = 0; d < D_; ++d) s += wrow[d] * tmp[d];
        out[(((size_t)b * LOUT + l) * C_ + c) * O_ + o] =
            s + bs[c * O_ + o] * S + bt[c];
    }
}

extern "C" void kernel_launch(void* const* d_in, const int* in_sizes, int n_in,
                              void* d_out, int out_size, void* d_ws, size_t ws_size,
                              hipStream_t stream) {
    const float* inp = (const float*)d_in[0];
    const float* Ws  = (const float*)d_in[1];
    const float* bs  = (const float*)d_in[2];
    const float* Wt  = (const float*)d_in[3];
    const float* bt  = (const float*)d_in[4];
    float* out = (float*)d_out;

    const size_t TMPB = (size_t)C_ * GM * D_ * 2;   // 31,981,568
    const size_t WSBB = (size_t)C_ * O_ * D_ * 2;   //  4,194,304

    if (ws_size >= TMPB + WSBB) {
        unsigned short* tmpb = (unsigned short*)d_ws;
        unsigned short* wsb  = (unsigned short*)((char*)d_ws + TMPB);
        prep<<<NFIRB + 2048, 256, 0, stream>>>(inp, Ws, Wt, tmpb, wsb);
        gemm_k<<<NMT * NNT * C_, 512, 0, stream>>>(tmpb, wsb, bs, Wt, bt, out);
    } else {
        naive_k<<<B_ * LOUT * C_, 256, 0, stream>>>(inp, Ws, bs, Wt, bt, out);
    }
}